// Round 9
// baseline (282.655 us; speedup 1.0000x reference)
//
#include <hip/hip_runtime.h>

// LinearAttention, fp16-MFMA restructuring (round 12).
//   xT   = transpose+cvt(x)          [b][l][c] f16
//   kv   = wkvT @ xT^T  (panel-GEMM) [b][f][l] f16, f<512:k, f>=512:v
//   stat = per-row {max, 1/sum(exp)} of k
//   ctxP = v softmax(k)^T partials (MFMA, K split 16)  [s][bh][e*64+d] f32
//   a2tT = (sum_s ctxP . w_out)^T    [b][c][g] f16
//   Mf   = a2tT @ wqs^T (gemm128)    [b][c][c'] f16
//   out  = Mf @ xT^T + b_out (panel-GEMM, fp32 out)
// Round-12: K1/K5 -> gemm_panel.  Diagnosis: all 5 prior GEMM structures
// (occ 17-47%, 2-8 barriers/tile, counted/drained vmcnt) plateau at ~50us
// because xT B-panels are re-read 8x/4x from L3/L2 (logical 512 MB in 50us
// = 10.2 TB/s, pinned between HBM 6.3 and L2 34.5; FETCH only 26 MB).
// gemm_panel keeps xT[128 l][512 c] RESIDENT in LDS (128 KB) per block and
// sweeps all M rows against it, streaming only wkvT/mf (L2-resident) via a
// 2x16KB dbuf.  LDS 160 KiB exactly (AITER attn uses 160KB on gfx950).
// Grid 256 = 1 block/CU, single round.  Sync = r6-verified machinery:
// asm ds_read + lgkm0 + sched_barrier; {BAR; STG(s+2); vmcnt(2); BAR}.
// MFMA k-order bitwise-identical to gemm128.  a2t reverted to round-9 form
// (v2's +87% L3 traffic cost more than its TLP bought: +9us).

typedef _Float16 half2_t __attribute__((ext_vector_type(2)));
typedef _Float16 half4_t __attribute__((ext_vector_type(4)));
typedef _Float16 half8_t __attribute__((ext_vector_type(8)));
typedef float    floatx4 __attribute__((ext_vector_type(4)));

#define SCALE_ 0.125f
#define CSPLIT 16

typedef __attribute__((address_space(3))) _Float16 lds_half;

__device__ __forceinline__ void async_lds16(const _Float16* g, _Float16* l) {
    __builtin_amdgcn_global_load_lds(
        (const __attribute__((address_space(1))) void*)g,
        (__attribute__((address_space(3))) void*)l,
        16, 0, 0);
}

__device__ __forceinline__ half8_t lds_read16(const lds_half* p) {
    half8_t r;
    asm volatile("ds_read_b128 %0, %1" : "=v"(r) : "v"(p));
    return r;
}

#define FENCE() asm volatile("" ::: "memory")
#define BAR()  do { FENCE(); __builtin_amdgcn_s_barrier(); FENCE(); } while (0)
#define VMW2() asm volatile("s_waitcnt vmcnt(2)" ::: "memory")
#define VMW0() asm volatile("s_waitcnt vmcnt(0)" ::: "memory")
#define LGKM0_SB() do { \
    asm volatile("s_waitcnt lgkmcnt(0)" ::: "memory"); \
    __builtin_amdgcn_sched_barrier(0); \
} while (0)

// ---------------- panel-resident GEMM -------------------------------------
// C[m][l] = sum_c A[m][c] * xT[b][l][c] (+bias[m]), M = FCH*128, K = 512.
// One block per (128-l panel, batch): xT panel resident in LDS; A streamed
// through 2x16KB dbuf.  512 threads, 8 waves (2 f x 4 l), 1 block/CU.
template <int FCH, typename OutT>
__global__ __launch_bounds__(512)
void gemm_panel(const _Float16* __restrict__ A, long aBatch,
                const _Float16* __restrict__ xTg,
                OutT* __restrict__ C, long cBatch,
                const float* __restrict__ bias)
{
    __shared__ _Float16 Pn[65536];      // [128 l][512 c] 128 KB, swizzled
    __shared__ _Float16 Ab[16384];      // [2][128 f][64 c] 32 KB, swizzled
    const int tid  = threadIdx.x;
    const int lane = tid & 63;
    const int wave = tid >> 6;
    const int wf = (wave & 1) * 64;     // f-offset within 128-chunk
    const int wl = (wave >> 1) * 32;    // l-offset within 128-panel

    // T1 XCD swizzle (256 blocks, %8==0): 32 same-batch panels per XCD
    // -> per-batch A (mf) is XCD-L2-resident.
    const int nwg = gridDim.x * gridDim.y;
    const int bid = blockIdx.x + gridDim.x * blockIdx.y;
    const int per = nwg >> 3;
    const int wg  = (bid & 7) * per + (bid >> 3);
    const int lp  = wg % gridDim.x;     // l-panel 0..31
    const int bz  = wg / gridDim.x;     // batch 0..7
    const int l0  = lp * 128;

    const _Float16* xb = xTg + (long)bz * 2097152 + (long)l0 * 512;
    const _Float16* Ag = A + (long)bz * aBatch;

    // ---- prologue: stage the panel (16 x gload_lds16 per thread).
    // T2 both-sides swizzle (rule #21): phys granule g at row r holds
    // logical granule g^(r&7); LDS dest linear, global source pre-swizzled.
#pragma unroll
    for (int i = 0; i < 16; ++i) {
        const int gi = i * 512 + tid;
        const int row = gi >> 6, g = gi & 63;
        async_lds16(xb + (long)row * 512 + ((g ^ (row & 7)) << 3), &Pn[gi * 8]);
    }

    // A-tile for step s: A[fc*128 .. +128][cs*64 .. +64], fc=s>>3, cs=s&7.
#define STG_A(s_, buf_) do { \
    const int fc_ = (s_) >> 3, cs_ = (s_) & 7; \
    _Pragma("unroll") \
    for (int j = 0; j < 2; ++j) { \
        const int gi_ = j * 512 + tid; \
        const int fl_ = gi_ >> 3, g_ = gi_ & 7; \
        async_lds16(Ag + (long)(fc_ * 128 + fl_) * 512 + cs_ * 64 \
                        + ((g_ ^ (fl_ & 7)) << 3), \
                    &Ab[(buf_) * 8192 + gi_ * 8]); \
    } \
} while (0)

    STG_A(0, 0);
    STG_A(1, 1);
    VMW0(); BAR();

    // fragment read offsets (swizzled side); row&7 == fm&7 for all tiles
    const int fm  = lane & 15;
    const int fkg = lane >> 4;
    int aRow[4], bRow[2], gxo[2];
#pragma unroll
    for (int i = 0; i < 4; ++i) aRow[i] = (wf + i * 16 + fm) << 6;
#pragma unroll
    for (int j = 0; j < 2; ++j) bRow[j] = (wl + j * 16 + fm) << 9;
#pragma unroll
    for (int k = 0; k < 2; ++k) gxo[k] = (((k * 4 + fkg) ^ (fm & 7)) << 3);

    const lds_half* Pn3 = (const lds_half*)&Pn[0];
    const lds_half* Ab3 = (const lds_half*)&Ab[0];

    const int em = (lane >> 4) * 4;
    const int en = lane & 15;
    OutT* Cb = C + (long)bz * cBatch;

    floatx4 acc[4][2];
#pragma unroll
    for (int i = 0; i < 4; ++i)
#pragma unroll
        for (int j = 0; j < 2; ++j) acc[i][j] = (floatx4)0.0f;

    const int S = FCH * 8;
    for (int s = 0; s < S; ++s) {
        const int cur = s & 1;
        const int cs  = s & 7;
        // A(s) verified landed at step s-1's vmcnt+BAR (all waves).
        half8_t aF[4][2], bF[2][2];
#pragma unroll
        for (int i = 0; i < 4; ++i)
#pragma unroll
            for (int k = 0; k < 2; ++k)
                aF[i][k] = lds_read16(Ab3 + cur * 8192 + aRow[i] + gxo[k]);
#pragma unroll
        for (int j = 0; j < 2; ++j)
#pragma unroll
            for (int k = 0; k < 2; ++k)
                bF[j][k] = lds_read16(Pn3 + bRow[j] + cs * 64 + gxo[k]);
        LGKM0_SB();
        __builtin_amdgcn_s_setprio(1);
#pragma unroll
        for (int i = 0; i < 4; ++i)
#pragma unroll
            for (int j = 0; j < 2; ++j)
#pragma unroll
                for (int k = 0; k < 2; ++k)
                    acc[i][j] = __builtin_amdgcn_mfma_f32_16x16x32_f16(
                        aF[i][k], bF[j][k], acc[i][j], 0, 0, 0);
        __builtin_amdgcn_s_setprio(0);
        BAR();                          // all waves done reading Ab[cur]
        if (s + 2 < S) {
            STG_A(s + 2, cur);          // overwrite just-freed buffer
            VMW2();                     // drains A(s+1); leaves A(s+2)
        } else {
            VMW0();
        }
        BAR();                          // everyone's A(s+1) landed
        if (cs == 7) {                  // chunk complete: write & reset acc
            const int fc = s >> 3;
#pragma unroll
            for (int i = 0; i < 4; ++i)
#pragma unroll
                for (int r = 0; r < 4; ++r) {
                    const int m = fc * 128 + wf + i * 16 + em + r;
                    const float bi = bias ? bias[m] : 0.0f;
#pragma unroll
                    for (int j = 0; j < 2; ++j) {
                        const int col = l0 + wl + j * 16 + en;
                        Cb[(long)m * 4096 + col] = (OutT)(acc[i][j][r] + bi);
                    }
                }
#pragma unroll
            for (int i = 0; i < 4; ++i)
#pragma unroll
                for (int j = 0; j < 2; ++j) acc[i][j] = (floatx4)0.0f;
        }
    }
#undef STG_A
}

// ---------------- 128x128 MFMA GEMM (round-8 form; K4m only) ---------------
template <typename OutT>
__global__ __launch_bounds__(512, 4)
void gemm128(const _Float16* __restrict__ A, long aBatch, int K,
             const _Float16* __restrict__ B, long bBatch,
             OutT* __restrict__ C, int ldc, long cBatch,
             const float* __restrict__ bias)
{
    __shared__ _Float16 smem[16384];
    const int tid  = threadIdx.x;
    const int lane = tid & 63;
    const int wave = tid >> 6;
    const int wm = (wave & 3) * 32;
    const int wn = (wave >> 2) * 64;

    const int nx = gridDim.x, ny = gridDim.y;
    const int nwg = nx * ny * gridDim.z;
    const int bid = blockIdx.x + nx * (blockIdx.y + ny * blockIdx.z);
    const int per = nwg >> 3;
    const int wg  = (bid & 7) * per + (bid >> 3);
    const int yb = wg % ny;
    const int xb = (wg / ny) % nx;
    const int zb = wg / (ny * nx);

    const int m0 = yb * 128;
    const int n0 = xb * 128;
    const long bz = zb;

    const int srow = tid >> 3;
    const int sxor = (((tid & 7) ^ (srow & 7)) << 3);
    const _Float16* pA = A + bz * aBatch + (long)(m0 + srow) * K + sxor;
    const _Float16* pB = B + bz * bBatch + (long)(n0 + srow) * K + sxor;
    _Float16* ldst = &smem[tid * 8];

    const int fm  = lane & 15;
    const int fkg = lane >> 4;
    int aRow[2], bRow[4], gxo[2];
#pragma unroll
    for (int i = 0; i < 2; ++i) aRow[i] = (wm + i * 16 + fm) << 6;
#pragma unroll
    for (int j = 0; j < 4; ++j) bRow[j] = 8192 + ((wn + j * 16 + fm) << 6);
#pragma unroll
    for (int k = 0; k < 2; ++k) gxo[k] = (((k * 4 + fkg) ^ (fm & 7)) << 3);

    floatx4 acc[2][4];
#pragma unroll
    for (int i = 0; i < 2; ++i)
#pragma unroll
        for (int j = 0; j < 4; ++j) acc[i][j] = (floatx4)0.0f;

    for (int t = 0; t < (K >> 6); ++t) {
        __syncthreads();
        async_lds16(pA + t * 64,                  ldst);
        async_lds16(pA + 64 * (long)K + t * 64,   ldst + 4096);
        async_lds16(pB + t * 64,                  ldst + 8192);
        async_lds16(pB + 64 * (long)K + t * 64,   ldst + 12288);
        VMW0();
        __syncthreads();

        half8_t aF[4], bF[8];
#pragma unroll
        for (int i = 0; i < 2; ++i)
#pragma unroll
            for (int k = 0; k < 2; ++k)
                aF[i * 2 + k] = *(const half8_t*)&smem[aRow[i] + gxo[k]];
#pragma unroll
        for (int j = 0; j < 4; ++j)
#pragma unroll
            for (int k = 0; k < 2; ++k)
                bF[j * 2 + k] = *(const half8_t*)&smem[bRow[j] + gxo[k]];
#pragma unroll
        for (int i = 0; i < 2; ++i)
#pragma unroll
            for (int j = 0; j < 4; ++j)
#pragma unroll
                for (int k = 0; k < 2; ++k)
                    acc[i][j] = __builtin_amdgcn_mfma_f32_16x16x32_f16(
                        aF[i * 2 + k], bF[j * 2 + k], acc[i][j], 0, 0, 0);
    }

    const int em = (lane >> 4) * 4;
    const int en = lane & 15;
    OutT* Cb = C + bz * cBatch;
#pragma unroll
    for (int i = 0; i < 2; ++i) {
#pragma unroll
        for (int r = 0; r < 4; ++r) {
            const int m = m0 + wm + i * 16 + em + r;
            const float bi = bias ? bias[m] : 0.0f;
#pragma unroll
            for (int j = 0; j < 4; ++j) {
                const int n = n0 + wn + j * 16 + en;
                Cb[(long)m * ldc + n] = (OutT)(acc[i][j][r] + bi);
            }
        }
    }
}

// ---------------- k_stats: per-row {max, 1/sum(exp)} of the k half ---------
__global__ __launch_bounds__(256)
void k_stats(const _Float16* __restrict__ kv, float2* __restrict__ stats)
{
    const int row = blockIdx.x;            // 0..4095
    const int b = row >> 9, f = row & 511;
    const _Float16* p = kv + (long)b * 4194304 + (long)f * 4096;
    const int tid = threadIdx.x;

    half8_t h0 = *(const half8_t*)(p + tid * 16);
    half8_t h1 = *(const half8_t*)(p + tid * 16 + 8);
    float v[16];
#pragma unroll
    for (int i = 0; i < 8; ++i) { v[i] = (float)h0[i]; v[8 + i] = (float)h1[i]; }

    float mx = -3.4e38f;
#pragma unroll
    for (int i = 0; i < 16; ++i) mx = fmaxf(mx, v[i]);
#pragma unroll
    for (int off = 32; off > 0; off >>= 1)
        mx = fmaxf(mx, __shfl_down(mx, off));

    __shared__ float red[8];
    if ((tid & 63) == 0) red[tid >> 6] = mx;
    __syncthreads();
    mx = fmaxf(fmaxf(red[0], red[1]), fmaxf(red[2], red[3]));

    float s = 0.0f;
#pragma unroll
    for (int i = 0; i < 16; ++i) s += __expf(v[i] - mx);
#pragma unroll
    for (int off = 32; off > 0; off >>= 1)
        s += __shfl_down(s, off);
    if ((tid & 63) == 0) red[4 + (tid >> 6)] = s;
    __syncthreads();
    if (tid == 0) {
        const float inv = 1.0f / (red[4] + red[5] + red[6] + red[7]);
        stats[row] = make_float2(mx, inv);
    }
}

// ---------------- context via MFMA, softmax fused (round-9 best form) ------
#define CPAD 40
__global__ __launch_bounds__(256)
void context_mfma(const _Float16* __restrict__ kv,
                  const float2* __restrict__ stats,
                  float* __restrict__ ctxP)
{
    const int bh = blockIdx.y;             // 0..63
    const int b = bh >> 3, h = bh & 7;
    const int l0 = blockIdx.x * (4096 / CSPLIT);

    __shared__ _Float16 As[64 * CPAD];
    __shared__ _Float16 Bs[64 * CPAD];
    const int tid  = threadIdx.x;
    const int lane = tid & 63;
    const int wave = tid >> 6;
    const int sr = tid >> 2;
    const int sc = (tid & 3) * 8;
    const int wm = (wave & 1) * 32;
    const int wn = (wave >> 1) * 32;
    const int fm = lane & 15;
    const int fk = (lane >> 4) * 8;

    const _Float16* vg = kv + (long)b * 4194304 + (long)(512 + h * 64 + sr) * 4096 + l0 + sc;
    const _Float16* kg = kv + (long)b * 4194304 + (long)(h * 64 + sr) * 4096 + l0 + sc;
    const float2 st = stats[b * 512 + h * 64 + sr];

    floatx4 acc[2][2];
#pragma unroll
    for (int i = 0; i < 2; ++i)
#pragma unroll
        for (int j = 0; j < 2; ++j) acc[i][j] = (floatx4)0.0f;

    for (int k0 = 0; k0 < 4096 / CSPLIT; k0 += 32) {
        const half8_t vv = *(const half8_t*)(vg + k0);
        const half8_t kk = *(const half8_t*)(kg + k0);
        half8_t pp;
#pragma unroll
        for (int j = 0; j < 8; ++j)
            pp[j] = (_Float16)(__expf((float)kk[j] - st.x) * st.y);
        __syncthreads();
        *(half8_t*)&As[sr * CPAD + sc] = vv;
        *(half8_t*)&Bs[sr * CPAD + sc] = pp;
        __syncthreads();

        half8_t a[2], b2[2];
#pragma unroll
        for (int i = 0; i < 2; ++i)
            a[i] = *(const half8_t*)&As[(wm + i * 16 + fm) * CPAD + fk];
#pragma unroll
        for (int j = 0; j < 2; ++j)
            b2[j] = *(const half8_t*)&Bs[(wn + j * 16 + fm) * CPAD + fk];
#pragma unroll
        for (int i = 0; i < 2; ++i)
#pragma unroll
            for (int j = 0; j < 2; ++j)
                acc[i][j] = __builtin_amdgcn_mfma_f32_16x16x32_f16(
                    a[i], b2[j], acc[i][j], 0, 0, 0);
    }

    const int em = (lane >> 4) * 4;
    const int en = lane & 15;
    float* base = ctxP + ((long)blockIdx.x * 64 + bh) * 4096;
#pragma unroll
    for (int i = 0; i < 2; ++i)
#pragma unroll
        for (int r = 0; r < 4; ++r)
#pragma unroll
            for (int j = 0; j < 2; ++j)
                base[(wm + i * 16 + em + r) * 64 + wn + j * 16 + en] = acc[i][j][r];
}

// ---------------- transpose + fp32->fp16 convert ---------------------------
__global__ __launch_bounds__(256)
void transpose_cvt(const float* __restrict__ src, int ld_s, long sB,
                   _Float16* __restrict__ dst, int ld_d, long dB)
{
    __shared__ float tile[64][65];
    const int c0 = blockIdx.x * 64;
    const int r0 = blockIdx.y * 64;
    const float* S = src + (long)blockIdx.z * sB;
    _Float16* D = dst + (long)blockIdx.z * dB;
    const int t = threadIdx.x;
    const int lr = t >> 4;
    const int lc = (t & 15) * 4;
#pragma unroll
    for (int i = 0; i < 4; ++i) {
        const float4 v = *(const float4*)(S + (long)(r0 + lr + 16 * i) * ld_s + c0 + lc);
        tile[lr + 16 * i][lc + 0] = v.x;
        tile[lr + 16 * i][lc + 1] = v.y;
        tile[lr + 16 * i][lc + 2] = v.z;
        tile[lr + 16 * i][lc + 3] = v.w;
    }
    __syncthreads();
    const int rl = (t & 15) * 4;
    const int cl = t >> 4;
#pragma unroll
    for (int i = 0; i < 4; ++i) {
        const int c = cl + 16 * i;
        half4_t o;
        o[0] = (_Float16)tile[rl + 0][c];
        o[1] = (_Float16)tile[rl + 1][c];
        o[2] = (_Float16)tile[rl + 2][c];
        o[3] = (_Float16)tile[rl + 3][c];
        *(half4_t*)(D + (long)(c0 + c) * ld_d + r0 + rl) = o;
    }
}

// ---------------- wqs[c'][g] = SCALE * w_qkv[c'][g], f16 -------------------
__global__ __launch_bounds__(256)
void scale_wq_kernel(const float* __restrict__ w_qkv, _Float16* __restrict__ wqs)
{
    const int c = blockIdx.x;
    const int t = threadIdx.x;
    const float2 v = *(const float2*)(w_qkv + (long)c * 1536 + t * 2);
    half2_t o;
    o[0] = (_Float16)(v.x * SCALE_);
    o[1] = (_Float16)(v.y * SCALE_);
    *(half2_t*)(wqs + (long)c * 512 + t * 2) = o;
}

// ---- a2tT[b][c][g] (round-9 form, reverted) -------------------------------
__global__ __launch_bounds__(256)
void a2t_kernel(const float* __restrict__ ctxP, const float* __restrict__ w_out,
                _Float16* __restrict__ a2tT)
{
    const int ct = blockIdx.x, h = blockIdx.y, b = blockIdx.z;
    __shared__ float cs[64][64];
    __shared__ float wsh[64][128];
    __shared__ _Float16 so[128][64];
    const int tid = threadIdx.x;
    {
        const int lr = tid >> 4, lc4 = (tid & 15) * 4;
        floatx4 accv[4];
#pragma unroll
        for (int i = 0; i < 4; ++i) accv[i] = (floatx4)0.0f;
        for (int s = 0; s < CSPLIT; ++s) {
            const float* cbase = ctxP + ((long)s * 64 + b * 8 + h) * 4096;
#pragma unroll
            for (int i = 0; i < 4; ++i)
                accv[i] += *(const floatx4*)(cbase + (lr + 16 * i) * 64 + lc4);
        }
#pragma unroll
        for (int i = 0; i < 4; ++i)
            *(floatx4*)&cs[lr + 16 * i][lc4] = accv[i];

        const float* wbase = w_out + (long)(h * 64) * 512 + ct * 128;
        const int wr = tid >> 5, wc4 = (tid & 31) * 4;
#pragma unroll
        for (int i = 0; i < 8; ++i) {
            const int e = wr + 8 * i;
            *(float4*)&wsh[e][wc4] = *(const float4*)(wbase + (long)e * 512 + wc4);
        }
    }
    __syncthreads();
    const int tx = tid & 15, ty = tid >> 4;
    float acc[4][8] = {};
    for (int e = 0; e < 64; ++e) {
        float a[4], bv[8];
#pragma unroll
        for (int i = 0; i < 4; ++i) a[i] = cs[e][ty * 4 + i];
#pragma unroll
        for (int j = 0; j < 8; ++j) bv[j] = wsh[e][tx * 8 + j];
#pragma unroll
        for (int i = 0; i < 4; ++i)
#pragma unroll
            for (int j = 0; j < 8; ++j)
                acc[i][j] = fmaf(a[i], bv[j], acc[i][j]);
    }
#pragma unroll
    for (int i = 0; i < 4; ++i)
#pragma unroll
        for (int j = 0; j < 8; ++j)
            so[tx * 8 + j][ty * 4 + i] = (_Float16)acc[i][j];
    __syncthreads();
#pragma unroll
    for (int q = tid; q < 1024; q += 256) {
        const int c_local = q >> 3, co = (q & 7) * 8;
        *(half8_t*)(a2tT + (long)b * 262144 + (long)(ct * 128 + c_local) * 512
                    + h * 64 + co) = *(const half8_t*)&so[c_local][co];
    }
}

extern "C" void kernel_launch(void* const* d_in, const int* in_sizes, int n_in,
                              void* d_out, int out_size, void* d_ws, size_t ws_size,
                              hipStream_t stream)
{
    const float* x      = (const float*)d_in[0];   // (8,512,4096)
    const float* w_qkv  = (const float*)d_in[1];   // (512,1536)
    const float* w_out  = (const float*)d_in[2];   // (512,512)
    const float* b_out  = (const float*)d_in[3];   // (512,)
    float* out = (float*)d_out;                    // (8,512,4096)

    char* wsb = (char*)d_ws;                       // ~122 MB total
    _Float16* kv   = (_Float16*)(wsb);             // 64 MB  [b][f][l]
    _Float16* xT   = (_Float16*)(wsb + 67108864);  // 32 MB  [b][l][c]
    _Float16* wkvT = (_Float16*)(wsb + 100663296); // 1 MB   [f][c]
    _Float16* wqs  = (_Float16*)(wsb + 101711872); // 0.5 MB [c'][g]
    _Float16* a2tT = (_Float16*)(wsb + 102236160); // 4 MB   [b][c][g]
    _Float16* mf   = (_Float16*)(wsb + 106430464); // 4 MB   [b][c][c']
    float*    ctxP = (float*)   (wsb + 110624768); // 16 MB  [s][bh][e*64+d]
    float2*   stats = (float2*)a2tT;               // aliases a2tT (dead span)

    // xT = transpose+cvt(x)
    transpose_cvt<<<dim3(64, 8, 8), 256, 0, stream>>>(
        x, 4096, 2097152L, xT, 512, 2097152L);
    // wkvT[f][c]
    transpose_cvt<<<dim3(16, 8, 1), 256, 0, stream>>>(
        w_qkv + 512, 1536, 0L, wkvT, 512, 0L);
    // wqs[c'][g] = SCALE * w_qkv[c'][g]
    scale_wq_kernel<<<dim3(512), 256, 0, stream>>>(w_qkv, wqs);

    // K1: kv = wkvT @ xT^T  (panel-resident: xT read once)
    gemm_panel<8, _Float16><<<dim3(32, 8), 512, 0, stream>>>(
        wkvT, 0L, xT, kv, 4194304L, nullptr);

    // K2: per-row softmax stats of the k half
    k_stats<<<dim3(4096), 256, 0, stream>>>(kv, stats);

    // K3: context partials via MFMA, softmax fused
    context_mfma<<<dim3(CSPLIT, 64), 256, 0, stream>>>(kv, stats, ctxP);

    // K4a: a2tT (round-9 form)
    a2t_kernel<<<dim3(4, 8, 8), 256, 0, stream>>>(ctxP, w_out, a2tT);

    // K4m: mf = a2tT @ wqs^T
    gemm128<_Float16><<<dim3(4, 4, 8), 512, 0, stream>>>(
        a2tT, 262144L, 512, wqs, 0L, mf, 512, 262144L, nullptr);

    // K5: out = mf @ xT^T + b_out  (panel-resident)
    gemm_panel<4, float><<<dim3(32, 8), 512, 0, stream>>>(
        mf, 262144L, xT, out, 2097152L, b_out);
}